// Round 3
// baseline (789.100 us; speedup 1.0000x reference)
//
#include <hip/hip_runtime.h>

#define N_OBJ 16384
#define N_REL 32768
#define HID 512
#define POOL 4096
#define NCLS 151
#define NRELCLS 51

typedef __attribute__((ext_vector_type(8))) short short8;
typedef __attribute__((ext_vector_type(4))) float f32x4;

__device__ __forceinline__ unsigned short f2bf(float x) {
    unsigned u = __float_as_uint(x);
    u += 0x7fff + ((u >> 16) & 1);   // round-to-nearest-even
    return (unsigned short)(u >> 16);
}

// ---------- generic f32 -> bf16 convert, 8 elems/thread ----------
__global__ void cvt_kernel(const float* __restrict__ in, unsigned short* __restrict__ out, long n8) {
    long i = (long)blockIdx.x * blockDim.x + threadIdx.x;
    if (i >= n8) return;
    const float4* p = (const float4*)in;
    float4 a = p[2 * i], b = p[2 * i + 1];
    short8 o;
    o[0] = f2bf(a.x); o[1] = f2bf(a.y); o[2] = f2bf(a.z); o[3] = f2bf(a.w);
    o[4] = f2bf(b.x); o[5] = f2bf(b.y); o[6] = f2bf(b.z); o[7] = f2bf(b.w);
    ((short8*)out)[i] = o;
}

// ---------- W_rel (51x4096) -> padded bf16 (64x4096), rows >=51 zero ----------
__global__ void cvt_wrel_kernel(const float* __restrict__ W, unsigned short* __restrict__ out) {
    int gid = blockIdx.x * 256 + threadIdx.x;   // 32768 threads, 8 elems each
    int row = gid >> 9;                          // 4096/8 = 512 chunks per row
    int c8 = (gid & 511) << 3;
    short8 o = {};
    if (row < NRELCLS) {
        const float* src = W + (long)row * POOL + c8;
        float4 a = *(const float4*)src, b = *(const float4*)(src + 4);
        o[0] = f2bf(a.x); o[1] = f2bf(a.y); o[2] = f2bf(a.z); o[3] = f2bf(a.w);
        o[4] = f2bf(b.x); o[5] = f2bf(b.y); o[6] = f2bf(b.z); o[7] = f2bf(b.w);
    }
    *(short8*)(out + (long)row * POOL + c8) = o;
}

// ---------- stage a [128 rows][64 cols] bf16 tile into LDS via global_load_lds w16 ----------
// LDS layout linear row-major (128B rows). 16 issues of 1KB; wave w does issues w*4..w*4+3.
// Linear (unswizzled) source: preserves adjacent-lane VMEM coalescing (round-2 lesson).
__device__ __forceinline__ void stage_tile128x64(const unsigned short* __restrict__ src,
                                                 unsigned short* lds,
                                                 int row0, int rowStrideElems, int col0,
                                                 int wave, int lane) {
    const char* s = (const char*)(src + (long)row0 * rowStrideElems + col0);
    long strideB = (long)rowStrideElems * 2;
#pragma unroll
    for (int is = 0; is < 4; ++is) {
        int issue = wave * 4 + is;
        const char* g = s + (long)(issue * 8 + (lane >> 3)) * strideB + (lane & 7) * 16;
        __builtin_amdgcn_global_load_lds((const __attribute__((address_space(1))) void*)g,
                                         (__attribute__((address_space(3))) void*)((char*)lds + issue * 1024),
                                         16, 0, 0);
    }
}

// ---------- GEMM1: edge_rep = edge_ctx(16384x512) @ W_emb(1024x512)^T + b, bf16 out ----------
__global__ __launch_bounds__(256) void gemm1_kernel(const unsigned short* __restrict__ A,
                                                    const unsigned short* __restrict__ B,
                                                    const float* __restrict__ bias,
                                                    unsigned short* __restrict__ C) {
    __shared__ __align__(16) unsigned short At[128 * 64];
    __shared__ __align__(16) unsigned short Bt[128 * 64];
    int row0 = blockIdx.x * 128, col0 = blockIdx.y * 128;
    int tid = threadIdx.x, wave = tid >> 6, lane = tid & 63;
    int wr = (wave >> 1) * 64, wc = (wave & 1) * 64;
    int lrow = lane & 15, lko = (lane >> 4) * 8;
    f32x4 acc[4][4] = {};
    for (int kt = 0; kt < HID / 64; ++kt) {
        stage_tile128x64(A, At, row0, HID, kt * 64, wave, lane);
        stage_tile128x64(B, Bt, col0, HID, kt * 64, wave, lane);
        __syncthreads();
#pragma unroll
        for (int ks = 0; ks < 2; ++ks) {
            short8 af[4], bf[4];
#pragma unroll
            for (int mi = 0; mi < 4; ++mi) af[mi] = *(const short8*)(At + (wr + 16 * mi + lrow) * 64 + ks * 32 + lko);
#pragma unroll
            for (int ni = 0; ni < 4; ++ni) bf[ni] = *(const short8*)(Bt + (wc + 16 * ni + lrow) * 64 + ks * 32 + lko);
#pragma unroll
            for (int mi = 0; mi < 4; ++mi)
#pragma unroll
                for (int ni = 0; ni < 4; ++ni)
                    acc[mi][ni] = __builtin_amdgcn_mfma_f32_16x16x32_bf16(af[mi], bf[ni], acc[mi][ni], 0, 0, 0);
        }
        __syncthreads();
    }
#pragma unroll
    for (int mi = 0; mi < 4; ++mi)
#pragma unroll
        for (int ni = 0; ni < 4; ++ni)
#pragma unroll
            for (int i = 0; i < 4; ++i) {
                int r = row0 + wr + 16 * mi + 4 * (lane >> 4) + i;
                int c = col0 + wc + 16 * ni + lrow;
                C[(long)r * 1024 + c] = f2bf(acc[mi][ni][i] + bias[c]);
            }
}

// ---------- gather: A2[r] = concat(edge_rep[h][0:512], edge_rep[t][512:1024]) ----------
__global__ void gather_kernel(const unsigned short* __restrict__ edge_rep,
                              const int* __restrict__ pair_idx,
                              unsigned short* __restrict__ A2) {
    long gid = (long)blockIdx.x * 256 + threadIdx.x;  // 32768 rows * 128 chunks of 16B
    int r = (int)(gid >> 7), j = (int)(gid & 127);
    int src = (j < 64) ? pair_idx[2 * r] : pair_idx[2 * r + 1];
    const uint4* s = (const uint4*)(edge_rep + (long)src * 1024);
    ((uint4*)(A2 + (long)r * 1024))[j] = s[j];
}

// ---------- init out = b_rel + freq_bias[op_h, op_t] ----------
__global__ void init_out_kernel(const int* __restrict__ pair_idx, const int* __restrict__ obj_preds,
                                const float* __restrict__ b_rel, const float* __restrict__ freq_bias,
                                float* __restrict__ out) {
    int r = blockIdx.x * 4 + (threadIdx.x >> 6);
    int lane = threadIdx.x & 63;
    if (lane < NRELCLS) {
        int h = pair_idx[2 * r], t = pair_idx[2 * r + 1];
        long idx = ((long)obj_preds[h] * NCLS + obj_preds[t]) * NRELCLS + lane;
        out[(long)r * NRELCLS + lane] = b_rel[lane] + freq_bias[idx];
    }
}

// ---------- fused: P = (A2 @ Wcat^T + bcat) * union ; out += P_bf16 @ Wrel^T ----------
// LDS: Pb (128x128, 32KB) ALIASES At+Bt (16KB each) -- never live simultaneously;
// every transition is barrier-separated.  48KB total -> 3 blocks/CU.
__global__ __launch_bounds__(256, 3) void fused_kernel(
    const unsigned short* __restrict__ A2,     // 32768x1024 bf16
    const unsigned short* __restrict__ Wcat,   // 4096x1024 bf16
    const unsigned short* __restrict__ Wrelp,  // 64x4096 bf16 (padded)
    const float* __restrict__ unionf,          // 32768x4096 f32
    const float* __restrict__ bcat,            // 4096
    float* __restrict__ out) {                 // 32768x51
    __shared__ __align__(16) char smem[48 * 1024];
    unsigned short* At = (unsigned short*)smem;              // [128][64], GEMM2 phase
    unsigned short* Bt = (unsigned short*)(smem + 16384);    // [128][64], GEMM2 phase
    unsigned short* Pb = (unsigned short*)smem;              // [128][128], GEMM3 phase (aliases At+Bt)
    unsigned short* Wr = (unsigned short*)(smem + 32768);    // [64][128]
    int row0 = blockIdx.x * 128;
    int split = blockIdx.y;   // 0..2; chunk range [c0,c1) of the 32 col-chunks
    int c0 = (split * 32) / 3, c1 = ((split + 1) * 32) / 3;
    int tid = threadIdx.x, wave = tid >> 6, lane = tid & 63;
    int wr = (wave >> 1) * 64, wc = (wave & 1) * 64;
    int lrow = lane & 15, lko = (lane >> 4) * 8;
    f32x4 acc3[2][4] = {};

    for (int c = c0; c < c1; ++c) {
        int cb = c * 128;
        f32x4 acc2[4][4] = {};
        // ---- GEMM2 over K=1024 ----
        for (int kt = 0; kt < 16; ++kt) {
            stage_tile128x64(A2, At, row0, 1024, kt * 64, wave, lane);
            stage_tile128x64(Wcat, Bt, cb, 1024, kt * 64, wave, lane);
            __syncthreads();
#pragma unroll
            for (int ks = 0; ks < 2; ++ks) {
                short8 af[4], bf[4];
#pragma unroll
                for (int mi = 0; mi < 4; ++mi) af[mi] = *(const short8*)(At + (wr + 16 * mi + lrow) * 64 + ks * 32 + lko);
#pragma unroll
                for (int ni = 0; ni < 4; ++ni) bf[ni] = *(const short8*)(Bt + (wc + 16 * ni + lrow) * 64 + ks * 32 + lko);
#pragma unroll
                for (int mi = 0; mi < 4; ++mi)
#pragma unroll
                    for (int ni = 0; ni < 4; ++ni)
                        acc2[mi][ni] = __builtin_amdgcn_mfma_f32_16x16x32_bf16(af[mi], bf[ni], acc2[mi][ni], 0, 0, 0);
            }
            __syncthreads();
        }
        // ---- stage Wrel chunk (64 rows x 128 cols, 256B rows) ----
#pragma unroll
        for (int is = 0; is < 4; ++is) {
            int issue = wave * 4 + is;
            const char* g = (const char*)(Wrelp + (long)(issue * 4 + (lane >> 4)) * POOL + cb) + (lane & 15) * 16;
            __builtin_amdgcn_global_load_lds((const __attribute__((address_space(1))) void*)g,
                                             (__attribute__((address_space(3))) void*)((char*)Wr + issue * 1024),
                                             16, 0, 0);
        }
        // ---- bias + union multiply -> Pb (bf16, overwrites At/Bt region) ----
#pragma unroll
        for (int mi = 0; mi < 4; ++mi)
#pragma unroll
            for (int ni = 0; ni < 4; ++ni) {
                int pcol = wc + 16 * ni + lrow;
                float bc = bcat[cb + pcol];
#pragma unroll
                for (int i = 0; i < 4; ++i) {
                    int prow = wr + 16 * mi + 4 * (lane >> 4) + i;
                    float u = unionf[(long)(row0 + prow) * POOL + cb + pcol];
                    Pb[prow * 128 + pcol] = f2bf((acc2[mi][ni][i] + bc) * u);
                }
            }
        __syncthreads();   // Pb written, Wr staged (vmcnt drained by barrier)
        // ---- GEMM3: acc3 += Pb(128x128) @ Wrel_chunk(64x128)^T ; wave w owns rows 32w..32w+31 ----
#pragma unroll
        for (int ks = 0; ks < 4; ++ks) {
            short8 pa[2], wb[4];
#pragma unroll
            for (int mi = 0; mi < 2; ++mi) pa[mi] = *(const short8*)(Pb + (wave * 32 + 16 * mi + lrow) * 128 + ks * 32 + lko);
#pragma unroll
            for (int ni = 0; ni < 4; ++ni) wb[ni] = *(const short8*)(Wr + (16 * ni + lrow) * 128 + ks * 32 + lko);
#pragma unroll
            for (int mi = 0; mi < 2; ++mi)
#pragma unroll
                for (int ni = 0; ni < 4; ++ni)
                    acc3[mi][ni] = __builtin_amdgcn_mfma_f32_16x16x32_bf16(pa[mi], wb[ni], acc3[mi][ni], 0, 0, 0);
        }
        __syncthreads();   // protect Pb/Wr before next chunk overwrites
    }
    // ---- epilogue: accumulate partial into out ----
#pragma unroll
    for (int mi = 0; mi < 2; ++mi)
#pragma unroll
        for (int ni = 0; ni < 4; ++ni)
#pragma unroll
            for (int i = 0; i < 4; ++i) {
                int r = row0 + wave * 32 + 16 * mi + 4 * (lane >> 4) + i;
                int cc = 16 * ni + lrow;
                if (cc < NRELCLS) atomicAdd(out + (long)r * NRELCLS + cc, acc3[mi][ni][i]);
            }
}

extern "C" void kernel_launch(void* const* d_in, const int* in_sizes, int n_in,
                              void* d_out, int out_size, void* d_ws, size_t ws_size,
                              hipStream_t stream) {
    const float* edge_ctx  = (const float*)d_in[0];
    const float* unionf    = (const float*)d_in[1];
    const int*   pair_idx  = (const int*)d_in[2];
    const int*   obj_preds = (const int*)d_in[3];
    const float* W_emb     = (const float*)d_in[4];
    const float* b_emb     = (const float*)d_in[5];
    const float* W_cat     = (const float*)d_in[6];
    const float* b_cat     = (const float*)d_in[7];
    const float* W_rel     = (const float*)d_in[8];
    const float* b_rel     = (const float*)d_in[9];
    const float* freq_bias = (const float*)d_in[10];
    float* out = (float*)d_out;

    char* ws = (char*)d_ws;
    unsigned short* ecb   = (unsigned short*)ws; ws += (size_t)N_OBJ * HID * 2;   // 16MB
    unsigned short* Wembb = (unsigned short*)ws; ws += (size_t)1024 * HID * 2;    // 1MB
    unsigned short* Wcatb = (unsigned short*)ws; ws += (size_t)POOL * 1024 * 2;   // 8MB
    unsigned short* Wrelb = (unsigned short*)ws; ws += (size_t)64 * POOL * 2;     // 0.5MB
    unsigned short* erep  = (unsigned short*)ws; ws += (size_t)N_OBJ * 1024 * 2;  // 32MB
    unsigned short* A2    = (unsigned short*)ws; ws += (size_t)N_REL * 1024 * 2;  // 64MB

    cvt_kernel<<<4096, 256, 0, stream>>>(edge_ctx, ecb, (long)N_OBJ * HID / 8);
    cvt_kernel<<<256, 256, 0, stream>>>(W_emb, Wembb, (long)1024 * HID / 8);
    cvt_kernel<<<2048, 256, 0, stream>>>(W_cat, Wcatb, (long)POOL * 1024 / 8);
    cvt_wrel_kernel<<<128, 256, 0, stream>>>(W_rel, Wrelb);
    gemm1_kernel<<<dim3(128, 8), 256, 0, stream>>>(ecb, Wembb, b_emb, erep);
    gather_kernel<<<16384, 256, 0, stream>>>(erep, pair_idx, A2);
    init_out_kernel<<<8192, 256, 0, stream>>>(pair_idx, obj_preds, b_rel, freq_bias, out);
    fused_kernel<<<dim3(256, 3), 256, 0, stream>>>(A2, Wcatb, Wrelb, unionf, b_cat, out);
}

// Round 5
// 564.988 us; speedup vs baseline: 1.3967x; 1.3967x over previous
//
#include <hip/hip_runtime.h>

#define N_OBJ 16384
#define N_REL 32768
#define HID 512
#define POOL 4096
#define NCLS 151
#define NRELCLS 51

#define AS1 __attribute__((address_space(1)))
#define AS3 __attribute__((address_space(3)))

typedef __attribute__((ext_vector_type(8))) short short8;
typedef __attribute__((ext_vector_type(4))) float f32x4;

__device__ __forceinline__ unsigned short f2bf(float x) {
    unsigned u = __float_as_uint(x);
    u += 0x7fff + ((u >> 16) & 1);   // round-to-nearest-even
    return (unsigned short)(u >> 16);
}

// ---------- generic f32 -> bf16 convert, 8 elems/thread ----------
__global__ void cvt_kernel(const float* __restrict__ in, unsigned short* __restrict__ out, long n8) {
    long i = (long)blockIdx.x * blockDim.x + threadIdx.x;
    if (i >= n8) return;
    const float4* p = (const float4*)in;
    float4 a = p[2 * i], b = p[2 * i + 1];
    short8 o;
    o[0] = f2bf(a.x); o[1] = f2bf(a.y); o[2] = f2bf(a.z); o[3] = f2bf(a.w);
    o[4] = f2bf(b.x); o[5] = f2bf(b.y); o[6] = f2bf(b.z); o[7] = f2bf(b.w);
    ((short8*)out)[i] = o;
}

// ---------- W_rel (51x4096) -> padded bf16 (64x4096), rows >=51 zero ----------
__global__ void cvt_wrel_kernel(const float* __restrict__ W, unsigned short* __restrict__ out) {
    int gid = blockIdx.x * 256 + threadIdx.x;
    int row = gid >> 9;
    int c8 = (gid & 511) << 3;
    short8 o = {};
    if (row < NRELCLS) {
        const float* src = W + (long)row * POOL + c8;
        float4 a = *(const float4*)src, b = *(const float4*)(src + 4);
        o[0] = f2bf(a.x); o[1] = f2bf(a.y); o[2] = f2bf(a.z); o[3] = f2bf(a.w);
        o[4] = f2bf(b.x); o[5] = f2bf(b.y); o[6] = f2bf(b.z); o[7] = f2bf(b.w);
    }
    *(short8*)(out + (long)row * POOL + c8) = o;
}

// ---------- stage a [128 rows][64 cols] bf16 tile into LDS (GEMM1 helper) ----------
__device__ __forceinline__ void stage_tile128x64(const unsigned short* __restrict__ src,
                                                 unsigned short* lds,
                                                 int row0, int rowStrideElems, int col0,
                                                 int wave, int lane) {
    const char* s = (const char*)(src + (long)row0 * rowStrideElems + col0);
    long strideB = (long)rowStrideElems * 2;
#pragma unroll
    for (int is = 0; is < 4; ++is) {
        int issue = wave * 4 + is;
        const char* g = s + (long)(issue * 8 + (lane >> 3)) * strideB + (lane & 7) * 16;
        __builtin_amdgcn_global_load_lds((const AS1 void*)g,
                                         (AS3 void*)((char*)lds + issue * 1024),
                                         16, 0, 0);
    }
}

// ---------- GEMM1: edge_rep = edge_ctx(16384x512) @ W_emb(1024x512)^T + b, bf16 out ----------
__global__ __launch_bounds__(256) void gemm1_kernel(const unsigned short* __restrict__ A,
                                                    const unsigned short* __restrict__ B,
                                                    const float* __restrict__ bias,
                                                    unsigned short* __restrict__ C) {
    __shared__ __align__(16) unsigned short At[128 * 64];
    __shared__ __align__(16) unsigned short Bt[128 * 64];
    int row0 = blockIdx.x * 128, col0 = blockIdx.y * 128;
    int tid = threadIdx.x, wave = tid >> 6, lane = tid & 63;
    int wr = (wave >> 1) * 64, wc = (wave & 1) * 64;
    int lrow = lane & 15, lko = (lane >> 4) * 8;
    f32x4 acc[4][4] = {};
    for (int kt = 0; kt < HID / 64; ++kt) {
        stage_tile128x64(A, At, row0, HID, kt * 64, wave, lane);
        stage_tile128x64(B, Bt, col0, HID, kt * 64, wave, lane);
        __syncthreads();
#pragma unroll
        for (int ks = 0; ks < 2; ++ks) {
            short8 af[4], bf[4];
#pragma unroll
            for (int mi = 0; mi < 4; ++mi) af[mi] = *(const short8*)(At + (wr + 16 * mi + lrow) * 64 + ks * 32 + lko);
#pragma unroll
            for (int ni = 0; ni < 4; ++ni) bf[ni] = *(const short8*)(Bt + (wc + 16 * ni + lrow) * 64 + ks * 32 + lko);
#pragma unroll
            for (int mi = 0; mi < 4; ++mi)
#pragma unroll
                for (int ni = 0; ni < 4; ++ni)
                    acc[mi][ni] = __builtin_amdgcn_mfma_f32_16x16x32_bf16(af[mi], bf[ni], acc[mi][ni], 0, 0, 0);
        }
        __syncthreads();
    }
#pragma unroll
    for (int mi = 0; mi < 4; ++mi)
#pragma unroll
        for (int ni = 0; ni < 4; ++ni)
#pragma unroll
            for (int i = 0; i < 4; ++i) {
                int r = row0 + wr + 16 * mi + 4 * (lane >> 4) + i;
                int c = col0 + wc + 16 * ni + lrow;
                C[(long)r * 1024 + c] = f2bf(acc[mi][ni][i] + bias[c]);
            }
}

// ---------- gather: A2[r] = concat(edge_rep[h][0:512], edge_rep[t][512:1024]) ----------
__global__ void gather_kernel(const unsigned short* __restrict__ edge_rep,
                              const int* __restrict__ pair_idx,
                              unsigned short* __restrict__ A2) {
    long gid = (long)blockIdx.x * 256 + threadIdx.x;
    int r = (int)(gid >> 7), j = (int)(gid & 127);
    int src = (j < 64) ? pair_idx[2 * r] : pair_idx[2 * r + 1];
    const uint4* s = (const uint4*)(edge_rep + (long)src * 1024);
    ((uint4*)(A2 + (long)r * 1024))[j] = s[j];
}

// ---------- init out = b_rel + freq_bias[op_h, op_t] ----------
__global__ void init_out_kernel(const int* __restrict__ pair_idx, const int* __restrict__ obj_preds,
                                const float* __restrict__ b_rel, const float* __restrict__ freq_bias,
                                float* __restrict__ out) {
    int r = blockIdx.x * 4 + (threadIdx.x >> 6);
    int lane = threadIdx.x & 63;
    if (lane < NRELCLS) {
        int h = pair_idx[2 * r], t = pair_idx[2 * r + 1];
        long idx = ((long)obj_preds[h] * NCLS + obj_preds[t]) * NRELCLS + lane;
        out[(long)r * NRELCLS + lane] = b_rel[lane] + freq_bias[idx];
    }
}

// ======================================================================
// fused: P = (A2 @ Wcat^T + bcat) * union ; out += P_bf16 @ Wrel^T
// 256x256 tile, 8 waves, BK=32, TRIPLE-buffered LDS, counted-vmcnt pipeline.
// LDS map (98304 B): A slots 3x16KB @0 ; B slots 3x16KB @49152.
// Epilogue aliases: Pb[256][128] (64KB) @0 ; Wr[2][64][128] (32KB) @65536.
// Staging swizzle (involution, 16B granules within 64B rows): c ^= (row&3)<<4,
// applied to BOTH the global source address and the ds_read address (rule #21).
// Pb/Wr swizzle (256B rows): c ^= (row&7)<<4.
// LDS dest of global_load_lds is WAVE-UNIFORM (i*8192 + w*1024); HW adds lane*16.
// ======================================================================
__device__ __forceinline__ void stage_ab(const char* __restrict__ A2b, const char* __restrict__ Wcb,
                                         char* lds, int slot, int t, int row0, int col0,
                                         int w, int lane) {
    int kb = t * 64;   // byte offset of this K-step in a 2048B row
#pragma unroll
    for (int i = 0; i < 2; ++i) {
        int obase = i * 8192 + w * 1024;     // wave-uniform LDS byte within 16KB tile
        int o = obase + lane * 16;           // this lane's linear byte
        int row = o >> 6, cin = o & 63;
        int c = cin ^ ((row & 3) << 4);      // pre-swizzled source column
        __builtin_amdgcn_global_load_lds((const AS1 void*)(A2b + (long)(row0 + row) * 2048 + kb + c),
                                         (AS3 void*)(lds + slot + obase), 16, 0, 0);
        __builtin_amdgcn_global_load_lds((const AS1 void*)(Wcb + (long)(col0 + row) * 2048 + kb + c),
                                         (AS3 void*)(lds + 49152 + slot + obase), 16, 0, 0);
    }
}

__device__ __forceinline__ void kstep(const char* lds, int slot, int wr, int wc, int lrow, int lcb,
                                      f32x4 acc[8][4]) {
    const char* A = lds + slot;
    const char* B = lds + 49152 + slot;
    short8 bfr[4];
#pragma unroll
    for (int ni = 0; ni < 4; ++ni) {
        int r = wc + 16 * ni + lrow;
        bfr[ni] = *(const short8*)(B + r * 64 + (lcb ^ ((r & 3) << 4)));
    }
    __builtin_amdgcn_s_setprio(1);
#pragma unroll
    for (int mi = 0; mi < 8; ++mi) {
        int r = wr + 16 * mi + lrow;
        short8 a = *(const short8*)(A + r * 64 + (lcb ^ ((r & 3) << 4)));
#pragma unroll
        for (int ni = 0; ni < 4; ++ni)
            acc[mi][ni] = __builtin_amdgcn_mfma_f32_16x16x32_bf16(a, bfr[ni], acc[mi][ni], 0, 0, 0);
    }
    __builtin_amdgcn_s_setprio(0);
}

__global__ __launch_bounds__(512, 2) void fused_kernel(
    const unsigned short* __restrict__ A2,     // 32768x1024 bf16
    const unsigned short* __restrict__ Wcat,   // 4096x1024 bf16
    const unsigned short* __restrict__ Wrelp,  // 64x4096 bf16 (padded)
    const float* __restrict__ unionf,          // 32768x4096 f32
    const float* __restrict__ bcat,            // 4096
    float* __restrict__ out) {                 // 32768x51
    __shared__ __align__(16) char lds[98304];
    int row0 = blockIdx.x * 256, col0 = blockIdx.y * 256;
    int tid = threadIdx.x, w = tid >> 6, lane = tid & 63;
    int wr = (w >> 2) * 128, wc = (w & 3) * 64;
    int lrow = lane & 15, lcb = (lane >> 4) * 16;
    const char* A2b = (const char*)A2;
    const char* Wcb = (const char*)Wcat;
    f32x4 acc2[8][4] = {};

    // prologue: stage K0 -> slot0, K1 -> slot1
    stage_ab(A2b, Wcb, lds, 0, 0, row0, col0, w, lane);
    stage_ab(A2b, Wcb, lds, 16384, 1, row0, col0, w, lane);

    int slot = 0, stslot = 32768;
    for (int t = 0; t < 31; ++t) {
        // retire exactly K_t's 4 loads (FIFO: K_t oldest of <=8 outstanding)
        asm volatile("s_waitcnt vmcnt(4)" ::: "memory");
        __builtin_amdgcn_s_barrier();          // K_t visible to all; slot (t+2)%3 readers done
        __builtin_amdgcn_sched_barrier(0);
        if (t < 30) stage_ab(A2b, Wcb, lds, stslot, t + 2, row0, col0, w, lane);
        kstep(lds, slot, wr, wc, lrow, lcb, acc2);
        slot = (slot == 32768) ? 0 : slot + 16384;
        stslot = (stslot == 32768) ? 0 : stslot + 16384;
    }
    // t = 31: only K31's 4 loads can be outstanding
    asm volatile("s_waitcnt vmcnt(0)" ::: "memory");
    __builtin_amdgcn_s_barrier();
    __builtin_amdgcn_sched_barrier(0);
    kstep(lds, slot, wr, wc, lrow, lcb, acc2);

    // ---- epilogue: repurpose LDS (all GEMM2 reads consumed by MFMAs) ----
    asm volatile("s_waitcnt lgkmcnt(0)" ::: "memory");
    __builtin_amdgcn_sched_barrier(0);
    __builtin_amdgcn_s_barrier();
    __builtin_amdgcn_sched_barrier(0);

    // stage Wrel both 128-col halves: [64][128] each, 256B rows, swizzled
#pragma unroll
    for (int h = 0; h < 2; ++h)
#pragma unroll
        for (int i = 0; i < 2; ++i) {
            int obase = i * 8192 + w * 1024;     // wave-uniform LDS dest
            int o = obase + lane * 16;
            int rw = o >> 8, cin = o & 255;
            int c = cin ^ ((rw & 7) << 4);
            __builtin_amdgcn_global_load_lds(
                (const AS1 void*)((const char*)Wrelp + (long)rw * 8192 + (col0 + h * 128) * 2 + c),
                (AS3 void*)(lds + 65536 + h * 16384 + obase), 16, 0, 0);
        }

    f32x4 acc3[2][4] = {};
#pragma unroll
    for (int h = 0; h < 2; ++h) {
        if (((w & 3) >> 1) == h) {
            int pc0 = ((w & 3) & 1) * 64;
            float bcv[4];
#pragma unroll
            for (int ni = 0; ni < 4; ++ni) bcv[ni] = bcat[col0 + h * 128 + pc0 + 16 * ni + lrow];
#pragma unroll
            for (int mi = 0; mi < 8; ++mi)
#pragma unroll
                for (int ni = 0; ni < 4; ++ni) {
                    int pcol = pc0 + 16 * ni + lrow;
#pragma unroll
                    for (int i = 0; i < 4; ++i) {
                        int prow = wr + 16 * mi + 4 * (lane >> 4) + i;
                        float u = unionf[(long)(row0 + prow) * 4096 + col0 + h * 128 + pcol];
                        *(unsigned short*)(lds + prow * 256 + ((pcol * 2) ^ ((prow & 7) << 4)))
                            = f2bf((acc2[mi][ni][i] + bcv[ni]) * u);
                    }
                }
        }
        // publish Pb ds_writes + ensure Wr staged, then barrier
        asm volatile("s_waitcnt vmcnt(0) lgkmcnt(0)" ::: "memory");
        __builtin_amdgcn_sched_barrier(0);
        __builtin_amdgcn_s_barrier();
        __builtin_amdgcn_sched_barrier(0);
        // GEMM3 on half h: acc3 += Pb(256x128) @ Wr_h(64x128)^T ; wave owns rows w*32..+31
#pragma unroll
        for (int ks = 0; ks < 4; ++ks) {
            int cb2 = ks * 64 + lcb;   // K-step stride is 64 BYTES (32 bf16) -- r4 bug was ks*32
            short8 wb[4], pa[2];
#pragma unroll
            for (int ni = 0; ni < 4; ++ni) {
                int r = 16 * ni + lrow;
                wb[ni] = *(const short8*)(lds + 65536 + h * 16384 + r * 256 + (cb2 ^ ((r & 7) << 4)));
            }
#pragma unroll
            for (int mi = 0; mi < 2; ++mi) {
                int r = w * 32 + 16 * mi + lrow;
                pa[mi] = *(const short8*)(lds + r * 256 + (cb2 ^ ((r & 7) << 4)));
            }
#pragma unroll
            for (int mi = 0; mi < 2; ++mi)
#pragma unroll
                for (int ni = 0; ni < 4; ++ni)
                    acc3[mi][ni] = __builtin_amdgcn_mfma_f32_16x16x32_bf16(pa[mi], wb[ni], acc3[mi][ni], 0, 0, 0);
        }
        if (h == 0) {   // Pb about to be overwritten by half 1; reads were consumed by MFMAs
            __builtin_amdgcn_s_barrier();
            __builtin_amdgcn_sched_barrier(0);
        }
    }
    // ---- accumulate partial into out ----
#pragma unroll
    for (int mi = 0; mi < 2; ++mi)
#pragma unroll
        for (int ni = 0; ni < 4; ++ni)
#pragma unroll
            for (int i = 0; i < 4; ++i) {
                int r = row0 + w * 32 + 16 * mi + 4 * (lane >> 4) + i;
                int cc = 16 * ni + lrow;
                if (cc < NRELCLS) atomicAdd(out + (long)r * NRELCLS + cc, acc3[mi][ni][i]);
            }
}

extern "C" void kernel_launch(void* const* d_in, const int* in_sizes, int n_in,
                              void* d_out, int out_size, void* d_ws, size_t ws_size,
                              hipStream_t stream) {
    const float* edge_ctx  = (const float*)d_in[0];
    const float* unionf    = (const float*)d_in[1];
    const int*   pair_idx  = (const int*)d_in[2];
    const int*   obj_preds = (const int*)d_in[3];
    const float* W_emb     = (const float*)d_in[4];
    const float* b_emb     = (const float*)d_in[5];
    const float* W_cat     = (const float*)d_in[6];
    const float* b_cat     = (const float*)d_in[7];
    const float* W_rel     = (const float*)d_in[8];
    const float* b_rel     = (const float*)d_in[9];
    const float* freq_bias = (const float*)d_in[10];
    float* out = (float*)d_out;

    char* ws = (char*)d_ws;
    unsigned short* ecb   = (unsigned short*)ws; ws += (size_t)N_OBJ * HID * 2;   // 16MB
    unsigned short* Wembb = (unsigned short*)ws; ws += (size_t)1024 * HID * 2;    // 1MB
    unsigned short* Wcatb = (unsigned short*)ws; ws += (size_t)POOL * 1024 * 2;   // 8MB
    unsigned short* Wrelb = (unsigned short*)ws; ws += (size_t)64 * POOL * 2;     // 0.5MB
    unsigned short* erep  = (unsigned short*)ws; ws += (size_t)N_OBJ * 1024 * 2;  // 32MB
    unsigned short* A2    = (unsigned short*)ws; ws += (size_t)N_REL * 1024 * 2;  // 64MB

    cvt_kernel<<<4096, 256, 0, stream>>>(edge_ctx, ecb, (long)N_OBJ * HID / 8);
    cvt_kernel<<<256, 256, 0, stream>>>(W_emb, Wembb, (long)1024 * HID / 8);
    cvt_kernel<<<2048, 256, 0, stream>>>(W_cat, Wcatb, (long)POOL * 1024 / 8);
    cvt_wrel_kernel<<<128, 256, 0, stream>>>(W_rel, Wrelb);
    gemm1_kernel<<<dim3(128, 8), 256, 0, stream>>>(ecb, Wembb, b_emb, erep);
    gather_kernel<<<16384, 256, 0, stream>>>(erep, pair_idx, A2);
    init_out_kernel<<<8192, 256, 0, stream>>>(pair_idx, obj_preds, b_rel, freq_bias, out);
    fused_kernel<<<dim3(128, 16), 512, 0, stream>>>(A2, Wcatb, Wrelb, unionf, b_cat, out);
}